// Round 20
// baseline (866.882 us; speedup 1.0000x reference)
//
#include <hip/hip_runtime.h>
#include <hip/hip_fp16.h>

#define D 64
#define PW2 128               // nodes per partition
#define PSH2 7
#define EPB 2048              // edges per sweep block
#define SLOT 4096             // per-partition edge-slot capacity (mean 2048)

// ---------- wave/block scan helpers ----------
__device__ __forceinline__ int wave_iscan64(int v, int lane) {
#pragma unroll
    for (int off = 1; off < 64; off <<= 1) {
        int u = __shfl_up(v, off, 64);
        if (lane >= off) v += u;
    }
    return v;
}

__device__ __forceinline__ int block_iscan512(int v, int t, int* wsum) {
    int lane = t & 63, wave = t >> 6;
    __syncthreads();
    int s = wave_iscan64(v, lane);
    if (lane == 63) wsum[wave] = s;
    __syncthreads();
    if (wave == 0) {
        int wv = (lane < 8) ? wsum[lane] : 0;
        int ws = wave_iscan64(wv, lane);
        if (lane < 8) wsum[lane] = ws - wv;
    }
    __syncthreads();
    return s + wsum[wave];
}

// ---------- zero lookback status ----------
__global__ void k_zero(unsigned int* __restrict__ p, int n4) {
    int i = blockIdx.x * blockDim.x + threadIdx.x;
    if (i < n4) *(uint4*)&p[i * 4] = make_uint4(0, 0, 0, 0);
}

// ---------- single-pass hist + decoupled-lookback + scatter ----------
__global__ __launch_bounds__(512) void k_sweep(const int* __restrict__ src,
        const int* __restrict__ dst, int E, int NP,
        unsigned int* __restrict__ status, int* __restrict__ csr_e) {
    __shared__ int lhist[512];
    __shared__ int cur[512];
    int t = threadIdx.x, b = blockIdx.x;
    for (int i = t; i < NP; i += 512) lhist[i] = 0;
    __syncthreads();
    int e = b * EPB + t * 4;
    if (e + 3 < E) {
        int4 d4 = *(const int4*)&dst[e];
        atomicAdd(&lhist[d4.x >> PSH2], 1);
        atomicAdd(&lhist[d4.y >> PSH2], 1);
        atomicAdd(&lhist[d4.z >> PSH2], 1);
        atomicAdd(&lhist[d4.w >> PSH2], 1);
    } else {
        for (int k = 0; k < 4; ++k)
            if (e + k < E) atomicAdd(&lhist[dst[e + k] >> PSH2], 1);
    }
    __syncthreads();
    // publish aggregate / lookback for cross-block exclusive prefix (bin t)
    if (t < NP) {
        unsigned agg = (unsigned)lhist[t];
        size_t me = (size_t)b * NP + t;
        if (b == 0) {
            __hip_atomic_store(&status[me], 0x80000000u | agg,
                               __ATOMIC_RELEASE, __HIP_MEMORY_SCOPE_AGENT);
            cur[t] = t * SLOT;
        } else {
            __hip_atomic_store(&status[me], 0x40000000u | agg,
                               __ATOMIC_RELEASE, __HIP_MEMORY_SCOPE_AGENT);
            unsigned excl = 0;
            int j = b - 1;
            while (j >= 0) {
                unsigned v = __hip_atomic_load(&status[(size_t)j * NP + t],
                                   __ATOMIC_ACQUIRE, __HIP_MEMORY_SCOPE_AGENT);
                if (v & 0x80000000u) { excl += v & 0x3FFFFFFFu; break; }
                if (v & 0x40000000u) { excl += v & 0x3FFFFFFFu; --j; }
                // else: spin (predecessor not published yet)
            }
            __hip_atomic_store(&status[me], 0x80000000u | (excl + agg),
                               __ATOMIC_RELEASE, __HIP_MEMORY_SCOPE_AGENT);
            cur[t] = t * SLOT + (int)excl;
        }
    }
    __syncthreads();
    // scatter into per-partition slots
    if (e + 3 < E) {
        int4 s4 = *(const int4*)&src[e];
        int4 d4 = *(const int4*)&dst[e];
        int p0 = atomicAdd(&cur[d4.x >> PSH2], 1);
        csr_e[p0] = s4.x | ((d4.x & (PW2 - 1)) << 16);
        int p1 = atomicAdd(&cur[d4.y >> PSH2], 1);
        csr_e[p1] = s4.y | ((d4.y & (PW2 - 1)) << 16);
        int p2 = atomicAdd(&cur[d4.z >> PSH2], 1);
        csr_e[p2] = s4.z | ((d4.z & (PW2 - 1)) << 16);
        int p3 = atomicAdd(&cur[d4.w >> PSH2], 1);
        csr_e[p3] = s4.w | ((d4.w & (PW2 - 1)) << 16);
    } else {
        for (int k = 0; k < 4; ++k) {
            if (e + k < E) {
                int s = src[e + k], d = dst[e + k];
                int pos = atomicAdd(&cur[d >> PSH2], 1);
                csr_e[pos] = s | ((d & (PW2 - 1)) << 16);
            }
        }
    }
}

// ---------- fine sort + dinv + fused z = fp16((x@W1)*dinv) ----------
__global__ __launch_bounds__(512) void k_sort2zw(const int* __restrict__ csr_e,
        const unsigned int* __restrict__ status, int NB, int NP, int n,
        const float* __restrict__ x, const float* __restrict__ W1,
        int* __restrict__ csr_src, int* __restrict__ row_ptr,
        int* __restrict__ row_cnt, float* __restrict__ dinv,
        __half* __restrict__ zh) {
    __shared__ int wsum[8];
    __shared__ int cnt[PW2];
    __shared__ int cursor[PW2];
    __shared__ float ldv[PW2];
    __shared__ float lrow[8][D];
    int t = threadIdx.x, p = blockIdx.x;
    int beg = p * SLOT;
    int total = (int)(status[(size_t)(NB - 1) * NP + p] & 0x3FFFFFFFu);
    int end = beg + total;

    if (t < PW2) cnt[t] = 0;
    __syncthreads();
    for (int i = beg + t; i < end; i += 512) atomicAdd(&cnt[csr_e[i] >> 16], 1);
    __syncthreads();
    int val = (t < PW2) ? cnt[t] : 0;
    int incl = block_iscan512(val, t, wsum);
    int excl = incl - val;
    if (t < PW2) {
        cursor[t] = beg + excl;
        int node = p * PW2 + t;
        float dv = rsqrtf((float)(val + 1));   // +1 self-loop
        ldv[t] = dv;
        if (node < n) {
            row_ptr[node] = beg + excl;
            row_cnt[node] = val;
            dinv[node] = dv;
        }
    }
    __syncthreads();
    for (int i = beg + t; i < end; i += 512) {
        int e = csr_e[i];
        int q = atomicAdd(&cursor[e >> 16], 1);  // LDS atomic
        csr_src[q] = e & 0xFFFF;
    }

    // fused zw: 8 waves x 16 nodes, W1 column in regs, reg-double-buffered row load
    int wave = t >> 6, lane = t & 63;
    float w1c[D];
#pragma unroll
    for (int d = 0; d < D; ++d) w1c[d] = W1[d * D + lane];
    int r0 = wave * 16;
    int node0 = p * PW2 + r0;
    float curx = 0.0f;
    if (node0 < n) curx = x[(size_t)node0 * D + lane];
    for (int k = 0; k < 16; ++k) {
        int r = r0 + k;
        int node = p * PW2 + r;
        if (node >= n) break;                  // wave-uniform
        float nxt = 0.0f;
        if (k + 1 < 16 && node + 1 < n) nxt = x[(size_t)(node + 1) * D + lane];
        lrow[wave][lane] = curx;
        __builtin_amdgcn_wave_barrier();
        float h = 0.0f;
#pragma unroll
        for (int db = 0; db < D; db += 4) {
            float4 rr = *(const float4*)&lrow[wave][db];
            h = fmaf(rr.x, w1c[db], h);
            h = fmaf(rr.y, w1c[db + 1], h);
            h = fmaf(rr.z, w1c[db + 2], h);
            h = fmaf(rr.w, w1c[db + 3], h);
        }
        zh[(size_t)node * D + lane] = __float2half(h * ldv[r]);
        __builtin_amdgcn_wave_barrier();
        curx = nxt;
    }
}

// ---------- gather z + fused relu/W2 epilogue -> sd ----------
__global__ __launch_bounds__(256) void k_gather(
        const __half2* __restrict__ zh, const float* __restrict__ dinv,
        const int* __restrict__ row_ptr, const int* __restrict__ row_cnt,
        const int* __restrict__ csr_src,
        const float* __restrict__ b1, const float* __restrict__ W2,
        float* __restrict__ sd, int n) {
    int tid = threadIdx.x;
    int wave = tid >> 6, lane = tid & 63;
    int eg = lane >> 3, dg = lane & 7;    // 8 edge groups x 8 dim lanes
    int v = blockIdx.x * 4 + wave;
    if (v >= n) return;
    float dv = dinv[v];
    int beg = row_ptr[v];
    int end = beg + row_cnt[v];

    float4 A = make_float4(0.f, 0.f, 0.f, 0.f);
    float4 B = make_float4(0.f, 0.f, 0.f, 0.f);
    float2 f;
#define ACC16(r)                                                        \
    {   __half2 h0 = *(__half2*)&(r).x, h1 = *(__half2*)&(r).y,         \
                h2 = *(__half2*)&(r).z, h3 = *(__half2*)&(r).w;         \
        f = __half22float2(h0); A.x += f.x; A.y += f.y;                 \
        f = __half22float2(h1); A.z += f.x; A.w += f.y;                 \
        f = __half22float2(h2); B.x += f.x; B.y += f.y;                 \
        f = __half22float2(h3); B.z += f.x; B.w += f.y; }

    if (eg == 0) {  // self-loop: + z[v]
        int4 r = *(const int4*)(zh + (size_t)v * 32 + dg * 4);
        ACC16(r);
    }
    int base = beg;
    for (; base + 16 <= end; base += 16) {
        int u0 = csr_src[base + eg];
        int u1 = csr_src[base + 8 + eg];
        int4 r0 = *(const int4*)(zh + (size_t)u0 * 32 + dg * 4);
        int4 r1 = *(const int4*)(zh + (size_t)u1 * 32 + dg * 4);
        ACC16(r0);
        ACC16(r1);
    }
    for (; base < end; base += 8) {
        int idx = base + eg;
        if (idx < end) {
            int u = csr_src[idx];
            int4 r = *(const int4*)(zh + (size_t)u * 32 + dg * 4);
            ACC16(r);
        }
    }
#undef ACC16
#pragma unroll
    for (int off = 8; off <= 32; off <<= 1) {
        A.x += __shfl_xor(A.x, off, 64); A.y += __shfl_xor(A.y, off, 64);
        A.z += __shfl_xor(A.z, off, 64); A.w += __shfl_xor(A.w, off, 64);
        B.x += __shfl_xor(B.x, off, 64); B.y += __shfl_xor(B.y, off, 64);
        B.z += __shfl_xor(B.z, off, 64); B.w += __shfl_xor(B.w, off, 64);
    }
    float4 b1a = *(const float4*)&b1[dg * 8];
    float4 b1b = *(const float4*)&b1[dg * 8 + 4];
    float4 w2a = *(const float4*)&W2[dg * 8];
    float4 w2b = *(const float4*)&W2[dg * 8 + 4];
    float part;
    part  = fmaxf(fmaf(dv, A.x, b1a.x), 0.f) * w2a.x;
    part += fmaxf(fmaf(dv, A.y, b1a.y), 0.f) * w2a.y;
    part += fmaxf(fmaf(dv, A.z, b1a.z), 0.f) * w2a.z;
    part += fmaxf(fmaf(dv, A.w, b1a.w), 0.f) * w2a.w;
    part += fmaxf(fmaf(dv, B.x, b1b.x), 0.f) * w2b.x;
    part += fmaxf(fmaf(dv, B.y, b1b.y), 0.f) * w2b.y;
    part += fmaxf(fmaf(dv, B.z, b1b.z), 0.f) * w2b.z;
    part += fmaxf(fmaf(dv, B.w, b1b.w), 0.f) * w2b.w;
    part += __shfl_xor(part, 1, 64);
    part += __shfl_xor(part, 2, 64);
    part += __shfl_xor(part, 4, 64);
    if (lane == 0) sd[v] = part * dv;    // s[v] * dinv[v]
}

// ---------- layer-2: 16 lanes per node gather over CSR ----------
__global__ __launch_bounds__(256) void k_out(const float* __restrict__ sd,
        const float* __restrict__ dinv, const int* __restrict__ row_ptr,
        const int* __restrict__ row_cnt, const int* __restrict__ csr_src,
        const float* __restrict__ b2, float* __restrict__ out, int n) {
    int t = blockIdx.x * blockDim.x + threadIdx.x;
    int v = t >> 4, r = t & 15;
    if (v >= n) return;
    int beg = row_ptr[v];
    int end = beg + row_cnt[v];
    float a = (r == 0) ? sd[v] : 0.0f;  // self-loop
    for (int i = beg + r; i < end; i += 16) a += sd[csr_src[i]];
    a += __shfl_xor(a, 1, 64);
    a += __shfl_xor(a, 2, 64);
    a += __shfl_xor(a, 4, 64);
    a += __shfl_xor(a, 8, 64);
    if (r == 0) out[v] = b2[0] + a * dinv[v];
}

extern "C" void kernel_launch(void* const* d_in, const int* in_sizes, int n_in,
                              void* d_out, int out_size, void* d_ws, size_t ws_size,
                              hipStream_t stream) {
    const float* x  = (const float*)d_in[0];
    const int*   ei = (const int*)d_in[1];
    const float* W1 = (const float*)d_in[2];
    const float* b1 = (const float*)d_in[3];
    const float* W2 = (const float*)d_in[4];
    const float* b2 = (const float*)d_in[5];

    int n = in_sizes[0] / D;   // 50000
    int E = in_sizes[1] / 2;   // 800000
    const int* src = ei;
    const int* dst = ei + E;

    int NP = (n + PW2 - 1) / PW2;    // 391 partitions (<= 512)
    int NB = (E + EPB - 1) / EPB;    // 391 sweep blocks

    char* ws = (char*)d_ws;
    auto take = [&](size_t bytes) {
        char* p = ws;
        ws += (bytes + 255) & ~(size_t)255;
        return p;
    };
    size_t stN = ((size_t)NB * NP + 3) & ~(size_t)3;
    unsigned int* status  = (unsigned int*)take(stN * sizeof(unsigned int));
    int*     csr_e     = (int*)take((size_t)NP * SLOT * sizeof(int));
    int*     csr_src   = (int*)take((size_t)NP * SLOT * sizeof(int));
    int*     row_ptr   = (int*)take((size_t)n * sizeof(int));
    int*     row_cnt   = (int*)take((size_t)n * sizeof(int));
    float*   dinv      = (float*)take((size_t)n * sizeof(float));
    float*   sd        = (float*)take((size_t)n * sizeof(float));
    __half*  zh        = (__half*)take((size_t)n * D * sizeof(__half));

    float* out = (float*)d_out;

    int st4 = (int)(stN / 4);
    k_zero<<<(st4 + 255) / 256, 256, 0, stream>>>(status, st4);
    k_sweep<<<NB, 512, 0, stream>>>(src, dst, E, NP, status, csr_e);
    k_sort2zw<<<NP, 512, 0, stream>>>(csr_e, status, NB, NP, n, x, W1,
                                      csr_src, row_ptr, row_cnt, dinv, zh);

    k_gather<<<(n + 3) / 4, 256, 0, stream>>>((const __half2*)zh, dinv, row_ptr,
                                              row_cnt, csr_src, b1, W2, sd, n);
    k_out<<<((size_t)n * 16 + 255) / 256, 256, 0, stream>>>(sd, dinv, row_ptr,
                                                            row_cnt, csr_src, b2,
                                                            out, n);
}

// Round 21
// 74.918 us; speedup vs baseline: 11.5710x; 11.5710x over previous
//
#include <hip/hip_runtime.h>
#include <hip/hip_fp16.h>

#define D 64
#define PW2 128               // nodes per partition
#define PSH2 7
#define EPB 2048              // edges per hist/scatter block; NB = ceil(E/EPB)

// ---------- wave/block scan helpers (barrier-light) ----------
__device__ __forceinline__ int wave_iscan64(int v, int lane) {
#pragma unroll
    for (int off = 1; off < 64; off <<= 1) {
        int u = __shfl_up(v, off, 64);
        if (lane >= off) v += u;
    }
    return v;
}

// inclusive scan over 512 threads (8 waves); 3 barriers
__device__ __forceinline__ int block_iscan512(int v, int t, int* wsum) {
    int lane = t & 63, wave = t >> 6;
    __syncthreads();                       // protect wsum reuse across calls
    int s = wave_iscan64(v, lane);
    if (lane == 63) wsum[wave] = s;
    __syncthreads();
    if (wave == 0) {
        int wv = (lane < 8) ? wsum[lane] : 0;
        int ws = wave_iscan64(wv, lane);
        if (lane < 8) wsum[lane] = ws - wv;  // exclusive offset of wave `lane`
    }
    __syncthreads();
    return s + wsum[wave];
}

// ---------- pass 1: per-block LDS histogram over partitions (int4 loads) ----------
__global__ __launch_bounds__(512) void k_hist(const int* __restrict__ dst, int E,
                                              int* __restrict__ counts, int NP) {
    extern __shared__ int lh[];
    int t = threadIdx.x, b = blockIdx.x;
    for (int i = t; i < NP; i += 512) lh[i] = 0;
    __syncthreads();
    int e = b * EPB + t * 4;
    if (e + 3 < E) {
        int4 d4 = *(const int4*)&dst[e];
        atomicAdd(&lh[d4.x >> PSH2], 1);
        atomicAdd(&lh[d4.y >> PSH2], 1);
        atomicAdd(&lh[d4.z >> PSH2], 1);
        atomicAdd(&lh[d4.w >> PSH2], 1);
    } else {
        for (int k = 0; k < 4; ++k)
            if (e + k < E) atomicAdd(&lh[dst[e + k] >> PSH2], 1);
    }
    __syncthreads();
    for (int i = t; i < NP; i += 512) counts[(size_t)b * NP + i] = lh[i];
}

// ---------- pass 2: per-bin exclusive scan over blocks (NB <= 512) ----------
__global__ __launch_bounds__(512) void k_scanA(int* __restrict__ counts, int NB, int NP,
                                               int* __restrict__ bin_total) {
    __shared__ int wsum[8];
    int t = threadIdx.x, bin = blockIdx.x;
    int v = (t < NB) ? counts[(size_t)t * NP + bin] : 0;
    int incl = block_iscan512(v, t, wsum);
    if (t < NB) counts[(size_t)t * NP + bin] = incl - v;  // exclusive within bin
    if (t == 511) bin_total[bin] = incl;
}

// ---------- pass 3: coarse scatter; bin_base scan via shuffles; int4 loads ----------
__global__ __launch_bounds__(512) void k_scatter(const int* __restrict__ src,
        const int* __restrict__ dst, int E, const int* __restrict__ counts,
        const int* __restrict__ bin_total, int NP, int* __restrict__ csr_e) {
    __shared__ int wsum[8];
    extern __shared__ int cur[];
    int t = threadIdx.x, b = blockIdx.x;
    int v = (t < NP) ? bin_total[t] : 0;
    int incl = block_iscan512(v, t, wsum);
    if (t < NP) cur[t] = counts[(size_t)b * NP + t] + (incl - v);  // + bin_base
    __syncthreads();
    int e = b * EPB + t * 4;
    if (e + 3 < E) {
        int4 s4 = *(const int4*)&src[e];
        int4 d4 = *(const int4*)&dst[e];
        int p0 = atomicAdd(&cur[d4.x >> PSH2], 1);
        csr_e[p0] = s4.x | ((d4.x & (PW2 - 1)) << 16);
        int p1 = atomicAdd(&cur[d4.y >> PSH2], 1);
        csr_e[p1] = s4.y | ((d4.y & (PW2 - 1)) << 16);
        int p2 = atomicAdd(&cur[d4.z >> PSH2], 1);
        csr_e[p2] = s4.z | ((d4.z & (PW2 - 1)) << 16);
        int p3 = atomicAdd(&cur[d4.w >> PSH2], 1);
        csr_e[p3] = s4.w | ((d4.w & (PW2 - 1)) << 16);
    } else {
        for (int k = 0; k < 4; ++k) {
            if (e + k < E) {
                int s = src[e + k], d = dst[e + k];
                int pos = atomicAdd(&cur[d >> PSH2], 1);
                csr_e[pos] = s | ((d & (PW2 - 1)) << 16);
            }
        }
    }
}

// ---------- pass 4: fine sort + dinv + fused z = fp16((x@W1)*dinv) ----------
__global__ __launch_bounds__(512) void k_sort2zw(const int* __restrict__ csr_e,
        const int* __restrict__ bin_total, int NP, int n,
        const float* __restrict__ x, const float* __restrict__ W1,
        int* __restrict__ csr_src, int* __restrict__ row_ptr,
        float* __restrict__ dinv, __half* __restrict__ zh) {
    __shared__ int wsum[8];
    __shared__ int cnt[PW2];
    __shared__ int cursor[PW2];
    __shared__ float ldv[PW2];
    __shared__ float lrow[8][D];
    __shared__ int s_beg, s_end;
    int t = threadIdx.x, p = blockIdx.x;

    // bin_base via in-LDS shuffle scan -> this partition's [beg,end)
    int bv = (t < NP) ? bin_total[t] : 0;
    int incl = block_iscan512(bv, t, wsum);
    if (t == p) { s_beg = incl - bv; s_end = incl; }
    if (t < PW2) cnt[t] = 0;
    __syncthreads();
    int beg = s_beg, end = s_end;

    // per-node counts
    for (int i = beg + t; i < end; i += 512) atomicAdd(&cnt[csr_e[i] >> 16], 1);
    __syncthreads();
    int val = (t < PW2) ? cnt[t] : 0;
    int incl2 = block_iscan512(val, t, wsum);
    int excl = incl2 - val;
    if (t < PW2) {
        cursor[t] = beg + excl;
        int node = p * PW2 + t;
        float dv = rsqrtf((float)(val + 1));   // +1 self-loop
        ldv[t] = dv;
        if (node <= n) {
            row_ptr[node] = beg + excl;        // node==n lands on E (last partition)
            if (node < n) dinv[node] = dv;
        }
    }
    __syncthreads();
    for (int i = beg + t; i < end; i += 512) {
        int e = csr_e[i];
        int q = atomicAdd(&cursor[e >> 16], 1);  // LDS atomic
        csr_src[q] = e & 0xFFFF;
    }

    // fused zw: 8 waves x 16 nodes, W1 column in regs
    int wave = t >> 6, lane = t & 63;
    float w1c[D];
#pragma unroll
    for (int d = 0; d < D; ++d) w1c[d] = W1[d * D + lane];
    int r0 = wave * 16;
    for (int k = 0; k < 16; ++k) {
        int r = r0 + k;
        int node = p * PW2 + r;
        if (node >= n) break;                  // wave-uniform
        lrow[wave][lane] = x[(size_t)node * D + lane];   // coalesced 256B
        __builtin_amdgcn_wave_barrier();
        float h = 0.0f;
#pragma unroll
        for (int db = 0; db < D; db += 4) {
            float4 rr = *(const float4*)&lrow[wave][db]; // broadcast ds_read_b128
            h = fmaf(rr.x, w1c[db], h);
            h = fmaf(rr.y, w1c[db + 1], h);
            h = fmaf(rr.z, w1c[db + 2], h);
            h = fmaf(rr.w, w1c[db + 3], h);
        }
        zh[(size_t)node * D + lane] = __float2half(h * ldv[r]);  // coalesced
        __builtin_amdgcn_wave_barrier();
    }
}

// ---------- gather z + fused relu/W2 epilogue -> sd; 8x8 wave, x2 unroll ----------
__global__ __launch_bounds__(256) void k_gather(
        const __half2* __restrict__ zh, const float* __restrict__ dinv,
        const int* __restrict__ row_ptr, const int* __restrict__ csr_src,
        const float* __restrict__ b1, const float* __restrict__ W2,
        float* __restrict__ sd, int n) {
    int tid = threadIdx.x;
    int wave = tid >> 6, lane = tid & 63;
    int eg = lane >> 3, dg = lane & 7;    // 8 edge groups x 8 dim lanes (16B each)
    int v = blockIdx.x * 4 + wave;
    if (v >= n) return;
    float dv = dinv[v];
    int beg = row_ptr[v], end = row_ptr[v + 1];

    float4 A = make_float4(0.f, 0.f, 0.f, 0.f);
    float4 B = make_float4(0.f, 0.f, 0.f, 0.f);
    float2 f;
#define ACC16(r)                                                        \
    {   __half2 h0 = *(__half2*)&(r).x, h1 = *(__half2*)&(r).y,         \
                h2 = *(__half2*)&(r).z, h3 = *(__half2*)&(r).w;         \
        f = __half22float2(h0); A.x += f.x; A.y += f.y;                 \
        f = __half22float2(h1); A.z += f.x; A.w += f.y;                 \
        f = __half22float2(h2); B.x += f.x; B.y += f.y;                 \
        f = __half22float2(h3); B.z += f.x; B.w += f.y; }

    if (eg == 0) {  // self-loop: + z[v]
        int4 r = *(const int4*)(zh + (size_t)v * 32 + dg * 4);
        ACC16(r);
    }
    int base = beg;
    for (; base + 16 <= end; base += 16) {   // 16 edges in flight, 2 chains
        int u0 = csr_src[base + eg];
        int u1 = csr_src[base + 8 + eg];
        int4 r0 = *(const int4*)(zh + (size_t)u0 * 32 + dg * 4);
        int4 r1 = *(const int4*)(zh + (size_t)u1 * 32 + dg * 4);
        ACC16(r0);
        ACC16(r1);
    }
    for (; base < end; base += 8) {
        int idx = base + eg;
        if (idx < end) {
            int u = csr_src[idx];
            int4 r = *(const int4*)(zh + (size_t)u * 32 + dg * 4);
            ACC16(r);
        }
    }
#undef ACC16
#pragma unroll
    for (int off = 8; off <= 32; off <<= 1) {   // reduce across edge groups
        A.x += __shfl_xor(A.x, off, 64); A.y += __shfl_xor(A.y, off, 64);
        A.z += __shfl_xor(A.z, off, 64); A.w += __shfl_xor(A.w, off, 64);
        B.x += __shfl_xor(B.x, off, 64); B.y += __shfl_xor(B.y, off, 64);
        B.z += __shfl_xor(B.z, off, 64); B.w += __shfl_xor(B.w, off, 64);
    }
    // epilogue: h = relu(dv*S + b1); partial = h . W2 over this lane's 8 dims
    float4 b1a = *(const float4*)&b1[dg * 8];
    float4 b1b = *(const float4*)&b1[dg * 8 + 4];
    float4 w2a = *(const float4*)&W2[dg * 8];
    float4 w2b = *(const float4*)&W2[dg * 8 + 4];
    float part;
    part  = fmaxf(fmaf(dv, A.x, b1a.x), 0.f) * w2a.x;
    part += fmaxf(fmaf(dv, A.y, b1a.y), 0.f) * w2a.y;
    part += fmaxf(fmaf(dv, A.z, b1a.z), 0.f) * w2a.z;
    part += fmaxf(fmaf(dv, A.w, b1a.w), 0.f) * w2a.w;
    part += fmaxf(fmaf(dv, B.x, b1b.x), 0.f) * w2b.x;
    part += fmaxf(fmaf(dv, B.y, b1b.y), 0.f) * w2b.y;
    part += fmaxf(fmaf(dv, B.z, b1b.z), 0.f) * w2b.z;
    part += fmaxf(fmaf(dv, B.w, b1b.w), 0.f) * w2b.w;
    part += __shfl_xor(part, 1, 64);
    part += __shfl_xor(part, 2, 64);
    part += __shfl_xor(part, 4, 64);
    if (lane == 0) sd[v] = part * dv;    // s[v] * dinv[v]
}

// ---------- layer-2: 16 lanes per node gather over CSR ----------
__global__ __launch_bounds__(256) void k_out(const float* __restrict__ sd,
        const float* __restrict__ dinv, const int* __restrict__ row_ptr,
        const int* __restrict__ csr_src, const float* __restrict__ b2,
        float* __restrict__ out, int n) {
    int t = blockIdx.x * blockDim.x + threadIdx.x;
    int v = t >> 4, r = t & 15;
    if (v >= n) return;
    int beg = row_ptr[v], end = row_ptr[v + 1];
    float a = (r == 0) ? sd[v] : 0.0f;  // self-loop
    for (int i = beg + r; i < end; i += 16) a += sd[csr_src[i]];
    a += __shfl_xor(a, 1, 64);
    a += __shfl_xor(a, 2, 64);
    a += __shfl_xor(a, 4, 64);
    a += __shfl_xor(a, 8, 64);
    if (r == 0) out[v] = b2[0] + a * dinv[v];
}

extern "C" void kernel_launch(void* const* d_in, const int* in_sizes, int n_in,
                              void* d_out, int out_size, void* d_ws, size_t ws_size,
                              hipStream_t stream) {
    const float* x  = (const float*)d_in[0];
    const int*   ei = (const int*)d_in[1];
    const float* W1 = (const float*)d_in[2];
    const float* b1 = (const float*)d_in[3];
    const float* W2 = (const float*)d_in[4];
    const float* b2 = (const float*)d_in[5];

    int n = in_sizes[0] / D;   // 50000
    int E = in_sizes[1] / 2;   // 800000
    const int* src = ei;
    const int* dst = ei + E;

    int NP = (n + PW2 - 1) / PW2;    // 391 partitions (<= 512)
    int NB = (E + EPB - 1) / EPB;    // 391 edge blocks (<= 512)

    char* ws = (char*)d_ws;
    auto take = [&](size_t bytes) {
        char* p = ws;
        ws += (bytes + 255) & ~(size_t)255;
        return p;
    };
    int*     counts    = (int*)take((size_t)NB * NP * sizeof(int));
    int*     bin_total = (int*)take((size_t)NP * sizeof(int));
    int*     csr_e     = (int*)take((size_t)E * sizeof(int));
    int*     csr_src   = (int*)take((size_t)E * sizeof(int));
    int*     row_ptr   = (int*)take((size_t)(n + 1) * sizeof(int));
    float*   dinv      = (float*)take((size_t)n * sizeof(float));
    float*   sd        = (float*)take((size_t)n * sizeof(float));
    __half*  zh        = (__half*)take((size_t)n * D * sizeof(__half));

    float* out = (float*)d_out;
    size_t ldsNP = (size_t)NP * sizeof(int);

    k_hist<<<NB, 512, ldsNP, stream>>>(dst, E, counts, NP);
    k_scanA<<<NP, 512, 0, stream>>>(counts, NB, NP, bin_total);
    k_scatter<<<NB, 512, ldsNP, stream>>>(src, dst, E, counts, bin_total, NP, csr_e);
    k_sort2zw<<<NP, 512, 0, stream>>>(csr_e, bin_total, NP, n, x, W1,
                                      csr_src, row_ptr, dinv, zh);

    k_gather<<<(n + 3) / 4, 256, 0, stream>>>((const __half2*)zh, dinv, row_ptr,
                                              csr_src, b1, W2, sd, n);
    k_out<<<((size_t)n * 16 + 255) / 256, 256, 0, stream>>>(sd, dinv, row_ptr, csr_src,
                                                            b2, out, n);
}